// Round 2
// baseline (340.020 us; speedup 1.0000x reference)
//
#include <hip/hip_runtime.h>
#include <hip/hip_bf16.h>

// Problem constants: B=4, S=2048, E=1024, H=16, D=64
#define BB 4
#define SS 2048
#define EE 1024
#define HH 16
#define DD 64
#define MM (BB*SS)   // 8192 rows

using f16x8 = __attribute__((ext_vector_type(8))) _Float16;
using f16x4 = __attribute__((ext_vector_type(4))) _Float16;
using f32x4 = __attribute__((ext_vector_type(4))) float;
using f32x16 = __attribute__((ext_vector_type(16))) float;

typedef __attribute__((address_space(3))) void       as3_void;
typedef const __attribute__((address_space(1))) void as1_cvoid;

// async global->LDS, 16B per lane; lds is wave-uniform base (HW adds lane*16)
__device__ __forceinline__ void async16(void* lds, const void* g) {
    __builtin_amdgcn_global_load_lds((as1_cvoid*)g, (as3_void*)lds, 16, 0, 0);
}

__device__ __forceinline__ f16x8 cvt8(const float* src) {
    const float4 v0 = *(const float4*)src;
    const float4 v1 = *(const float4*)(src + 4);
    f16x8 h;
    h[0] = (_Float16)v0.x; h[1] = (_Float16)v0.y;
    h[2] = (_Float16)v0.z; h[3] = (_Float16)v0.w;
    h[4] = (_Float16)v1.x; h[5] = (_Float16)v1.y;
    h[6] = (_Float16)v1.z; h[7] = (_Float16)v1.w;
    return h;
}

// ---- all converts (3 activations + 4 weights) in ONE launch ----
__global__ __launch_bounds__(256) void cvt_all(const float* __restrict__ q,
                                               const float* __restrict__ k,
                                               const float* __restrict__ v,
                                               const float* __restrict__ w0,
                                               const float* __restrict__ w1,
                                               const float* __restrict__ w2,
                                               const float* __restrict__ w3,
                                               _Float16* __restrict__ dq,
                                               _Float16* __restrict__ dk,
                                               _Float16* __restrict__ dv,
                                               _Float16* __restrict__ wf,
                                               int aN8, int wN8) {
    int seg = blockIdx.y;
    int i = blockIdx.x * 256 + threadIdx.x;
    const float* s; _Float16* d; int n8;
    if (seg < 3) {
        s = seg == 0 ? q : seg == 1 ? k : v;
        d = seg == 0 ? dq : seg == 1 ? dk : dv;
        n8 = aN8;
    } else {
        int t = seg - 3;
        s = t == 0 ? w0 : t == 1 ? w1 : t == 2 ? w2 : w3;
        d = wf + (size_t)t * EE * EE;
        n8 = wN8;
    }
    if (i < n8) ((f16x8*)d)[i] = cvt8(s + (size_t)i * 8);
}

// Band swizzle: 4-strip x 8-col super-tiles per XCD (1MB A + 2MB B < 4MB L2).
// fid&7 ~ XCD (round-robin dispatch heuristic).
__device__ __forceinline__ void swizzle512(int fid, int& m0, int& n0) {
    int xcd  = fid & 7;
    int s    = fid >> 3;              // 0..63
    int band = xcd + 8 * (s >> 5);    // 0..15 (4-strip bands)
    int w    = s & 31;
    m0 = (band * 4 + (w & 3)) * 128;
    n0 = (w >> 2) * 128;
}

// ---- QKV projections, z-merged, all-fp16, async16 both operands, BK=64 ----
// z==0 epilogue folds sm_scale*log2(e) into Q (free).
// z==2 epilogue stores V TRANSPOSED as Vt[b][h][d][s] (f16x4 packed stores)
// so the attention kernel can stage V via global_load_lds frag-linear.
__global__ __launch_bounds__(256) void gemm_qkv(const _Float16* __restrict__ A0,
                                                const _Float16* __restrict__ A1,
                                                const _Float16* __restrict__ A2,
                                                const _Float16* __restrict__ W,  // [3][E*E]
                                                _Float16* __restrict__ Cb,       // [3][M*E]
                                                int M, int N, int K) {
    constexpr int BM = 128, BN = 128, BK = 64;
    __shared__ alignas(16) _Float16 As[2][BM * 32];   // m97 layout per 32-wide k-half
    __shared__ alignas(16) _Float16 Bs[2][BN * 32];

    const int tid  = threadIdx.x;
    const int lane = tid & 63;
    const int wave = tid >> 6;
    const int wm   = (wave >> 1) * 64;
    const int wn   = (wave & 1) * 64;
    const int quad = lane >> 4;
    const int c    = lane & 15;
    int m0, n0;
    swizzle512(blockIdx.x, m0, n0);
    const int z = blockIdx.y;

    const _Float16* A  = z == 0 ? A0 : z == 1 ? A1 : A2;
    const _Float16* Bw = W + (size_t)z * EE * EE;
    _Float16* C = Cb + (size_t)z * MM * EE;
    const float osc = (z == 0) ? 0.18033688f : 1.0f;   // 0.125*log2(e) folded into Q

    f32x4 acc[4][4] = {};

    for (int k0 = 0; k0 < K; k0 += BK) {
#pragma unroll
        for (int p = 0; p < 4; ++p) {
            int half = p >> 1;
            int remb = (p & 1) * 256 + wave * 64;          // wave-uniform
            int rem  = remb + lane;
            int row  = rem >> 2, kc = (rem & 3) * 8;
            async16(&As[half][remb * 8], A  + (size_t)(m0 + row) * K + k0 + half * 32 + kc);
            async16(&Bs[half][remb * 8], Bw + (size_t)(n0 + row) * K + k0 + half * 32 + kc);
        }
        __syncthreads();

#pragma unroll
        for (int ks = 0; ks < 2; ++ks) {
            f16x8 af[4], bf[4];
#pragma unroll
            for (int i = 0; i < 4; ++i)
                af[i] = *(const f16x8*)&As[ks][(wm + i * 16 + c) * 32 + quad * 8];
#pragma unroll
            for (int j = 0; j < 4; ++j)
                bf[j] = *(const f16x8*)&Bs[ks][(wn + j * 16 + c) * 32 + quad * 8];
#pragma unroll
            for (int i = 0; i < 4; ++i)
#pragma unroll
                for (int j = 0; j < 4; ++j)
                    acc[i][j] = __builtin_amdgcn_mfma_f32_16x16x32_f16(af[i], bf[j], acc[i][j], 0, 0, 0);
        }
        __syncthreads();
    }

    if (z == 2) {
        // transposed V store: Vt[((b*HH+h)*DD+d)*SS + s], 4 consecutive s per thread
#pragma unroll
        for (int i = 0; i < 4; ++i)
#pragma unroll
            for (int j = 0; j < 4; ++j) {
                int col  = n0 + wn + j * 16 + c;          // E index = h*64+d
                int rowb = m0 + wm + i * 16 + quad * 4;   // global row = b*SS+s
                int bq = rowb >> 11, sI = rowb & 2047;
                f16x4 ov;
#pragma unroll
                for (int r = 0; r < 4; ++r) ov[r] = (_Float16)acc[i][j][r];
                *(f16x4*)&C[(((size_t)bq * HH + (col >> 6)) * DD + (col & 63)) * SS + sI] = ov;
            }
    } else {
#pragma unroll
        for (int i = 0; i < 4; ++i)
#pragma unroll
            for (int j = 0; j < 4; ++j)
#pragma unroll
                for (int r = 0; r < 4; ++r) {
                    int row = m0 + wm + i * 16 + quad * 4 + r;
                    int col = n0 + wn + j * 16 + c;
                    C[(size_t)row * N + col] = (_Float16)(acc[i][j][r] * osc);
                }
    }
}

// ---- output projection: fp32 out ----
__global__ __launch_bounds__(256) void gemm_wo(const _Float16* __restrict__ A,
                                               const _Float16* __restrict__ Bw,
                                               float* __restrict__ C,
                                               int M, int N, int K) {
    constexpr int BM = 128, BN = 128, BK = 64;
    __shared__ alignas(16) _Float16 As[2][BM * 32];
    __shared__ alignas(16) _Float16 Bs[2][BN * 32];

    const int tid  = threadIdx.x;
    const int lane = tid & 63;
    const int wave = tid >> 6;
    const int wm   = (wave >> 1) * 64;
    const int wn   = (wave & 1) * 64;
    const int quad = lane >> 4;
    const int c    = lane & 15;
    int m0, n0;
    swizzle512(blockIdx.x, m0, n0);

    f32x4 acc[4][4] = {};

    for (int k0 = 0; k0 < K; k0 += BK) {
#pragma unroll
        for (int p = 0; p < 4; ++p) {
            int half = p >> 1;
            int remb = (p & 1) * 256 + wave * 64;
            int rem  = remb + lane;
            int row  = rem >> 2, kc = (rem & 3) * 8;
            async16(&As[half][remb * 8], A  + (size_t)(m0 + row) * K + k0 + half * 32 + kc);
            async16(&Bs[half][remb * 8], Bw + (size_t)(n0 + row) * K + k0 + half * 32 + kc);
        }
        __syncthreads();

#pragma unroll
        for (int ks = 0; ks < 2; ++ks) {
            f16x8 af[4], bf[4];
#pragma unroll
            for (int i = 0; i < 4; ++i)
                af[i] = *(const f16x8*)&As[ks][(wm + i * 16 + c) * 32 + quad * 8];
#pragma unroll
            for (int j = 0; j < 4; ++j)
                bf[j] = *(const f16x8*)&Bs[ks][(wn + j * 16 + c) * 32 + quad * 8];
#pragma unroll
            for (int i = 0; i < 4; ++i)
#pragma unroll
                for (int j = 0; j < 4; ++j)
                    acc[i][j] = __builtin_amdgcn_mfma_f32_16x16x32_f16(af[i], bf[j], acc[i][j], 0, 0, 0);
        }
        __syncthreads();
    }

#pragma unroll
    for (int i = 0; i < 4; ++i)
#pragma unroll
        for (int j = 0; j < 4; ++j)
#pragma unroll
            for (int r = 0; r < 4; ++r) {
                int row = m0 + wm + i * 16 + quad * 4 + r;
                int col = n0 + wn + j * 16 + c;
                C[(size_t)row * N + col] = acc[i][j][r];
            }
}

// ---- Flash attention, 32x32 MFMA, all-async16 staging, in-register P ----
// V is pre-transposed (Vt[b][h][d][s]) so BOTH K and V tiles stage via
// global_load_lds with per-lane gathered global src into frag-linear LDS
// (conflict-free ds_read_b128 by construction). Single barrier per tile;
// K(t+1)/V(t+1) prefetch issues at tile start, drains at tile-end barrier
// (full tile of compute ~600cy >> L2 latency). Softmax fully in-register
// via swapped QK^T + cvt_pkrtz + permlane32_swap. Compute order
// QK0,QK1,sm0,PV01,sm1,PV23 lets sm1 VALU run under PV01's issued MFMAs.
__global__ __launch_bounds__(256, 4) void attn_kernel(const _Float16* __restrict__ Q,
                                                      const _Float16* __restrict__ K,
                                                      const _Float16* __restrict__ Vt,
                                                      _Float16* __restrict__ O) {
    constexpr int NT = SS / 64;
    __shared__ alignas(16) _Float16 Ks[2][8 * 512];   // 8 frags (kvt*4+ks) x 64 lanes x 8
    __shared__ alignas(16) _Float16 Vs[2][8 * 512];   // 8 frags (ks*2+dt) of V^T

    const int tid  = threadIdx.x;
    const int lane = tid & 63;
    const int wave = tid >> 6;
    const int l31  = lane & 31;
    const int hl   = lane >> 5;
    const int bh   = blockIdx.x;                      // bh-major: same-head q-tiles share L2
    const int b    = bh >> 4, h = bh & 15;
    const int q0   = blockIdx.y * 128;

    const _Float16* Qg  = Q  + (size_t)(b * SS + q0) * EE + h * DD;
    const _Float16* Kg  = K  + (size_t)(b * SS) * EE + h * DD;
    const _Float16* Vtg = Vt + (size_t)bh * DD * SS;

    // ---- Q fragments: global -> regs, once (B-operand, all 4 k-steps) ----
    f16x8 qf[4];
#pragma unroll
    for (int ks = 0; ks < 4; ++ks)
        qf[ks] = *(const f16x8*)(Qg + (size_t)(wave * 32 + l31) * EE + ks * 16 + hl * 8);

    // per-thread staging source pointers (advance by one tile each iter)
    const _Float16* kp[2];
    const _Float16* vp[2];
#pragma unroll
    for (int p = 0; p < 2; ++p) {
        int f = wave * 2 + p;
        int kvt = f >> 2, ksk = f & 3;            // K frag = kvt*4+ks
        kp[p] = Kg + (size_t)(kvt * 32 + l31) * EE + ksk * 16 + hl * 8;
        int ksv = f >> 1, dt = f & 1;             // V frag = ks*2+dt
        vp[p] = Vtg + (size_t)(dt * 32 + l31) * SS + ksv * 16 + hl * 8;
    }

    // ---- prologue: stage K(0),V(0) into buf0 ----
#pragma unroll
    for (int p = 0; p < 2; ++p) {
        int f = wave * 2 + p;
        async16(&Ks[0][f * 512], kp[p]);
        async16(&Vs[0][f * 512], vp[p]);
    }
    __syncthreads();

    float lsum = 0.f;
    f32x16 o0 = {}, o1 = {};

    for (int t = 0; t < NT; ++t) {
        const int buf = t & 1;

        // prefetch K(t+1),V(t+1) into buf^1 (drains at tile-end barrier)
        if (t + 1 < NT) {
#pragma unroll
            for (int p = 0; p < 2; ++p) {
                int f = wave * 2 + p;
                kp[p] += 64 * EE;
                vp[p] += 64;
                async16(&Ks[buf ^ 1][f * 512], kp[p]);
                async16(&Vs[buf ^ 1][f * 512], vp[p]);
            }
        }

        // ---- QK^T: both 32-kv subtiles issued back to back ----
        f32x16 sa = {}, sb = {};
        __builtin_amdgcn_s_setprio(1);
#pragma unroll
        for (int ks = 0; ks < 4; ++ks) {
            f16x8 af = *(const f16x8*)&Ks[buf][ks * 512 + lane * 8];
            sa = __builtin_amdgcn_mfma_f32_32x32x16_f16(af, qf[ks], sa, 0, 0, 0);
        }
#pragma unroll
        for (int ks = 0; ks < 4; ++ks) {
            f16x8 af = *(const f16x8*)&Ks[buf][(4 + ks) * 512 + lane * 8];
            sb = __builtin_amdgcn_mfma_f32_32x32x16_f16(af, qf[ks], sb, 0, 0, 0);
        }
        __builtin_amdgcn_s_setprio(0);

        // ---- softmax kvt0 -> pB[0..1] (in-register pack) ----
        f16x8 pB[4];
#pragma unroll
        for (int kvt = 0; kvt < 2; ++kvt) {
            const f32x16& s = kvt ? sb : sa;
            float p[16];
#pragma unroll
            for (int r = 0; r < 16; ++r) {
                p[r] = __builtin_amdgcn_exp2f(s[r]);
                lsum += p[r];
            }
            int w[8];
#pragma unroll
            for (int i = 0; i < 8; ++i)
                w[i] = __builtin_bit_cast(int, __builtin_amdgcn_cvt_pkrtz(p[2 * i], p[2 * i + 1]));
            asm("v_permlane32_swap_b32 %0, %1" : "+v"(w[0]), "+v"(w[2]));
            asm("v_permlane32_swap_b32 %0, %1" : "+v"(w[1]), "+v"(w[3]));
            asm("v_permlane32_swap_b32 %0, %1" : "+v"(w[4]), "+v"(w[6]));
            asm("v_permlane32_swap_b32 %0, %1" : "+v"(w[5]), "+v"(w[7]));
            int4 lo; lo.x = w[0]; lo.y = w[1]; lo.z = w[2]; lo.w = w[3];
            int4 hi; hi.x = w[4]; hi.y = w[5]; hi.z = w[6]; hi.w = w[7];
            pB[kvt * 2 + 0] = __builtin_bit_cast(f16x8, lo);
            pB[kvt * 2 + 1] = __builtin_bit_cast(f16x8, hi);

            // ---- PV for this kvt's two k-slices (MFMAs issue, VALU of next
            // softmax runs underneath) ----
            __builtin_amdgcn_s_setprio(1);
#pragma unroll
            for (int ks = kvt * 2; ks < kvt * 2 + 2; ++ks) {
                f16x8 v0 = *(const f16x8*)&Vs[buf][(ks * 2 + 0) * 512 + lane * 8];
                o0 = __builtin_amdgcn_mfma_f32_32x32x16_f16(v0, pB[ks], o0, 0, 0, 0);
                f16x8 v1 = *(const f16x8*)&Vs[buf][(ks * 2 + 1) * 512 + lane * 8];
                o1 = __builtin_amdgcn_mfma_f32_32x32x16_f16(v1, pB[ks], o1, 0, 0, 0);
            }
            __builtin_amdgcn_s_setprio(0);
        }

        __syncthreads();   // buf reads done by all waves; buf^1 prefetch drained
    }

    // ---- epilogue: l across lane-halves, normalize, packed 8B stores ----
    float lt  = lsum + __shfl_xor(lsum, 32);
    float inv = 1.0f / lt;
    _Float16* Og = O + (size_t)(b * SS + q0 + wave * 32 + l31) * EE + h * DD;
#pragma unroll
    for (int dt = 0; dt < 2; ++dt)
#pragma unroll
        for (int g = 0; g < 4; ++g) {
            f16x4 ov;
#pragma unroll
            for (int r = 0; r < 4; ++r) {
                float val = (dt == 0) ? o0[g * 4 + r] : o1[g * 4 + r];
                ov[r] = (_Float16)(val * inv);
            }
            *(f16x4*)&Og[dt * 32 + g * 8 + hl * 4] = ov;
        }
}

extern "C" void kernel_launch(void* const* d_in, const int* in_sizes, int n_in,
                              void* d_out, int out_size, void* d_ws, size_t ws_size,
                              hipStream_t stream) {
    const float* query = (const float*)d_in[0];
    const float* key   = (const float*)d_in[1];
    const float* value = (const float*)d_in[2];
    const float* Wq    = (const float*)d_in[3];
    const float* Wk    = (const float*)d_in[4];
    const float* Wv    = (const float*)d_in[5];
    const float* Wo    = (const float*)d_in[6];
    float* out = (float*)d_out;

    const size_t NE = (size_t)MM * EE;   // 8388608
    const size_t NW = (size_t)EE * EE;   // 1048576
    // ws: Qw,Kw,Vt (48MB) + Wf (8MB) + Qact/O (16MB) = 72 MiB
    _Float16* Qw   = (_Float16*)d_ws;
    _Float16* Kw   = Qw + NE;
    _Float16* Vw   = Kw + NE;            // holds TRANSPOSED V: [B][H][D][S]
    _Float16* Wf   = Vw + NE;            // [4][NW]
    _Float16* Qact = Wf + 4 * NW;        // query fp16; later attn O
    // K/V activations borrow d_out (32MB fp32) — dead before final GEMM writes it
    _Float16* Kact = (_Float16*)d_out;
    _Float16* Vact = Kact + NE;

    dim3 blk(256);
    const int wN8 = (int)(NW / 8), aN8 = (int)(NE / 8);

    // 1) all converts, one launch (weight segments early-exit past wN8)
    cvt_all<<<dim3(aN8 / 256, 7), blk, 0, stream>>>(query, key, value, Wq, Wk, Wv, Wo,
                                                    Qact, Kact, Vact, Wf, aN8, wN8);

    // 2) QKV projections, z=3, band-swizzled (Q folds cs; V stored transposed)
    gemm_qkv<<<dim3(512, 3), blk, 0, stream>>>(Qact, Kact, Vact, Wf, Qw, MM, EE, EE);

    // 3) attention -> Qact region (bh-major grid for XCD L2 locality)
    attn_kernel<<<dim3(BB * HH, SS / 128), blk, 0, stream>>>(Qw, Kw, Vw, Qact);

    // 4) output projection (writes all of d_out; Kact/Vact dead)
    gemm_wo<<<dim3(512), blk, 0, stream>>>(Qact, Wf + 3 * NW, out, MM, EE, EE);
}

// Round 4
// 337.603 us; speedup vs baseline: 1.0072x; 1.0072x over previous
//
#include <hip/hip_runtime.h>
#include <hip/hip_bf16.h>

// Problem constants: B=4, S=2048, E=1024, H=16, D=64
#define BB 4
#define SS 2048
#define EE 1024
#define HH 16
#define DD 64
#define MM (BB*SS)   // 8192 rows

using f16x8 = __attribute__((ext_vector_type(8))) _Float16;
using f16x4 = __attribute__((ext_vector_type(4))) _Float16;
using f32x4 = __attribute__((ext_vector_type(4))) float;
using f32x16 = __attribute__((ext_vector_type(16))) float;

typedef __attribute__((address_space(3))) void       as3_void;
typedef const __attribute__((address_space(1))) void as1_cvoid;

// async global->LDS, 16B per lane; lds is wave-uniform base (HW adds lane*16)
__device__ __forceinline__ void async16(void* lds, const void* g) {
    __builtin_amdgcn_global_load_lds((as1_cvoid*)g, (as3_void*)lds, 16, 0, 0);
}

__device__ __forceinline__ f16x8 cvt8(const float* src) {
    const float4 v0 = *(const float4*)src;
    const float4 v1 = *(const float4*)(src + 4);
    f16x8 h;
    h[0] = (_Float16)v0.x; h[1] = (_Float16)v0.y;
    h[2] = (_Float16)v0.z; h[3] = (_Float16)v0.w;
    h[4] = (_Float16)v1.x; h[5] = (_Float16)v1.y;
    h[6] = (_Float16)v1.z; h[7] = (_Float16)v1.w;
    return h;
}

// ---- all converts (3 activations + 4 weights) in ONE launch ----
__global__ __launch_bounds__(256) void cvt_all(const float* __restrict__ q,
                                               const float* __restrict__ k,
                                               const float* __restrict__ v,
                                               const float* __restrict__ w0,
                                               const float* __restrict__ w1,
                                               const float* __restrict__ w2,
                                               const float* __restrict__ w3,
                                               _Float16* __restrict__ dq,
                                               _Float16* __restrict__ dk,
                                               _Float16* __restrict__ dv,
                                               _Float16* __restrict__ wf,
                                               int aN8, int wN8) {
    int seg = blockIdx.y;
    int i = blockIdx.x * 256 + threadIdx.x;
    const float* s; _Float16* d; int n8;
    if (seg < 3) {
        s = seg == 0 ? q : seg == 1 ? k : v;
        d = seg == 0 ? dq : seg == 1 ? dk : dv;
        n8 = aN8;
    } else {
        int t = seg - 3;
        s = t == 0 ? w0 : t == 1 ? w1 : t == 2 ? w2 : w3;
        d = wf + (size_t)t * EE * EE;
        n8 = wN8;
    }
    if (i < n8) ((f16x8*)d)[i] = cvt8(s + (size_t)i * 8);
}

// Band swizzle: 4-strip x 8-col super-tiles per XCD (1MB A + 2MB B < 4MB L2).
// fid&7 ~ XCD (round-robin dispatch heuristic).
__device__ __forceinline__ void swizzle512(int fid, int& m0, int& n0) {
    int xcd  = fid & 7;
    int s    = fid >> 3;              // 0..63
    int band = xcd + 8 * (s >> 5);    // 0..15 (4-strip bands)
    int w    = s & 31;
    m0 = (band * 4 + (w & 3)) * 128;
    n0 = (w >> 2) * 128;
}

// ---- QKV projections, z-merged, all-fp16, async16 both operands, BK=64 ----
// z==0 epilogue folds sm_scale*log2(e) into Q (free).
// z==2 epilogue stores V TRANSPOSED as Vt[b][h][d][s] via an LDS bounce:
// wave tile -> swizzled [d][s] LDS -> ds_read_b128 -> COALESCED dwordx4
// stores (round 2's direct f16x4 scatter cost ~11us in write amplification).
__global__ __launch_bounds__(256) void gemm_qkv(const _Float16* __restrict__ A0,
                                                const _Float16* __restrict__ A1,
                                                const _Float16* __restrict__ A2,
                                                const _Float16* __restrict__ W,  // [3][E*E]
                                                _Float16* __restrict__ Cb,       // [3][M*E]
                                                int M, int N, int K) {
    constexpr int BM = 128, BN = 128, BK = 64;
    __shared__ alignas(16) _Float16 As[2][BM * 32];   // m97 layout per 32-wide k-half
    __shared__ alignas(16) _Float16 Bs[2][BN * 32];

    const int tid  = threadIdx.x;
    const int lane = tid & 63;
    const int wave = tid >> 6;
    const int wm   = (wave >> 1) * 64;
    const int wn   = (wave & 1) * 64;
    const int quad = lane >> 4;
    const int c    = lane & 15;
    int m0, n0;
    swizzle512(blockIdx.x, m0, n0);
    const int z = blockIdx.y;

    const _Float16* A  = z == 0 ? A0 : z == 1 ? A1 : A2;
    const _Float16* Bw = W + (size_t)z * EE * EE;
    _Float16* C = Cb + (size_t)z * MM * EE;
    const float osc = (z == 0) ? 0.18033688f : 1.0f;   // 0.125*log2(e) folded into Q

    f32x4 acc[4][4] = {};

    for (int k0 = 0; k0 < K; k0 += BK) {
#pragma unroll
        for (int p = 0; p < 4; ++p) {
            int half = p >> 1;
            int remb = (p & 1) * 256 + wave * 64;          // wave-uniform
            int rem  = remb + lane;
            int row  = rem >> 2, kc = (rem & 3) * 8;
            async16(&As[half][remb * 8], A  + (size_t)(m0 + row) * K + k0 + half * 32 + kc);
            async16(&Bs[half][remb * 8], Bw + (size_t)(n0 + row) * K + k0 + half * 32 + kc);
        }
        __syncthreads();

#pragma unroll
        for (int ks = 0; ks < 2; ++ks) {
            f16x8 af[4], bf[4];
#pragma unroll
            for (int i = 0; i < 4; ++i)
                af[i] = *(const f16x8*)&As[ks][(wm + i * 16 + c) * 32 + quad * 8];
#pragma unroll
            for (int j = 0; j < 4; ++j)
                bf[j] = *(const f16x8*)&Bs[ks][(wn + j * 16 + c) * 32 + quad * 8];
#pragma unroll
            for (int i = 0; i < 4; ++i)
#pragma unroll
                for (int j = 0; j < 4; ++j)
                    acc[i][j] = __builtin_amdgcn_mfma_f32_16x16x32_f16(af[i], bf[j], acc[i][j], 0, 0, 0);
        }
        __syncthreads();
    }

    if (z == 2) {
        // ---- transposed V epilogue via LDS bounce (coalesced stores) ----
        // Per wave: 8KB of dead As/Bs. Layout [d][64 s], s XOR-swizzled by
        // (d&7)<<3 so the column-strided f16x4 writes are 2-way (free).
        _Float16* tb = (wave < 2) ? ((_Float16*)As) + wave * 4096
                                  : ((_Float16*)Bs) + (wave - 2) * 4096;
#pragma unroll
        for (int i = 0; i < 4; ++i)
#pragma unroll
            for (int j = 0; j < 4; ++j) {
                int dl = j * 16 + c;            // local d 0..63
                int sl = i * 16 + quad * 4;     // local s 0..63 (4-aligned)
                f16x4 ov;
#pragma unroll
                for (int r = 0; r < 4; ++r) ov[r] = (_Float16)acc[i][j][r];
                *(f16x4*)&tb[dl * 64 + (sl ^ ((dl & 7) << 3))] = ov;
            }
        __syncthreads();
        // coalesced store: 8 lanes cover 128B (64 s) of one d row
        const int colbase = n0 + wn;            // 64-aligned -> head fixed per wave
        const int h  = colbase >> 6;
        const int rowb = m0 + wm;               // 64-aligned
        const int bq = rowb >> 11;
        const int s_base = rowb & 2047;
        const int dr0 = lane >> 3;
        const int sc  = (lane & 7) * 8;
        _Float16* Vtb = C + (((size_t)bq * HH + h) * DD) * SS;
#pragma unroll
        for (int dd = 0; dd < 8; ++dd) {
            int d = dd * 8 + dr0;
            f16x8 vv = *(const f16x8*)&tb[d * 64 + (sc ^ ((d & 7) << 3))];
            *(f16x8*)&Vtb[(size_t)d * SS + s_base + sc] = vv;
        }
    } else {
#pragma unroll
        for (int i = 0; i < 4; ++i)
#pragma unroll
            for (int j = 0; j < 4; ++j)
#pragma unroll
                for (int r = 0; r < 4; ++r) {
                    int row = m0 + wm + i * 16 + quad * 4 + r;
                    int col = n0 + wn + j * 16 + c;
                    C[(size_t)row * N + col] = (_Float16)(acc[i][j][r] * osc);
                }
    }
}

// ---- output projection: fp32 out ----
__global__ __launch_bounds__(256) void gemm_wo(const _Float16* __restrict__ A,
                                               const _Float16* __restrict__ Bw,
                                               float* __restrict__ C,
                                               int M, int N, int K) {
    constexpr int BM = 128, BN = 128, BK = 64;
    __shared__ alignas(16) _Float16 As[2][BM * 32];
    __shared__ alignas(16) _Float16 Bs[2][BN * 32];

    const int tid  = threadIdx.x;
    const int lane = tid & 63;
    const int wave = tid >> 6;
    const int wm   = (wave >> 1) * 64;
    const int wn   = (wave & 1) * 64;
    const int quad = lane >> 4;
    const int c    = lane & 15;
    int m0, n0;
    swizzle512(blockIdx.x, m0, n0);

    f32x4 acc[4][4] = {};

    for (int k0 = 0; k0 < K; k0 += BK) {
#pragma unroll
        for (int p = 0; p < 4; ++p) {
            int half = p >> 1;
            int remb = (p & 1) * 256 + wave * 64;
            int rem  = remb + lane;
            int row  = rem >> 2, kc = (rem & 3) * 8;
            async16(&As[half][remb * 8], A  + (size_t)(m0 + row) * K + k0 + half * 32 + kc);
            async16(&Bs[half][remb * 8], Bw + (size_t)(n0 + row) * K + k0 + half * 32 + kc);
        }
        __syncthreads();

#pragma unroll
        for (int ks = 0; ks < 2; ++ks) {
            f16x8 af[4], bf[4];
#pragma unroll
            for (int i = 0; i < 4; ++i)
                af[i] = *(const f16x8*)&As[ks][(wm + i * 16 + c) * 32 + quad * 8];
#pragma unroll
            for (int j = 0; j < 4; ++j)
                bf[j] = *(const f16x8*)&Bs[ks][(wn + j * 16 + c) * 32 + quad * 8];
#pragma unroll
            for (int i = 0; i < 4; ++i)
#pragma unroll
                for (int j = 0; j < 4; ++j)
                    acc[i][j] = __builtin_amdgcn_mfma_f32_16x16x32_f16(af[i], bf[j], acc[i][j], 0, 0, 0);
        }
        __syncthreads();
    }

#pragma unroll
    for (int i = 0; i < 4; ++i)
#pragma unroll
        for (int j = 0; j < 4; ++j)
#pragma unroll
            for (int r = 0; r < 4; ++r) {
                int row = m0 + wm + i * 16 + quad * 4 + r;
                int col = n0 + wn + j * 16 + c;
                C[(size_t)row * N + col] = acc[i][j][r];
            }
}

// ---- Flash attention, 32x32 MFMA, all-async16 staging, in-register P ----
// V is pre-transposed (Vt[b][h][d][s]) so BOTH K and V tiles stage via
// global_load_lds with per-lane gathered global src into frag-linear LDS
// (conflict-free ds_read_b128 by construction). Single barrier per tile;
// K(t+1)/V(t+1) prefetch issues at tile start, drains at tile-end barrier.
// Softmax fully in-register via swapped QK^T + cvt_pkrtz + permlane32_swap.
// QK issues sa/sb as two INTERLEAVED dependency chains; lsum uses 4 partial
// accumulators (FP add chains are not compiler-reassociable).
__global__ __launch_bounds__(256, 4) void attn_kernel(const _Float16* __restrict__ Q,
                                                      const _Float16* __restrict__ K,
                                                      const _Float16* __restrict__ Vt,
                                                      _Float16* __restrict__ O) {
    constexpr int NT = SS / 64;
    __shared__ alignas(16) _Float16 Ks[2][8 * 512];   // 8 frags (kvt*4+ks) x 64 lanes x 8
    __shared__ alignas(16) _Float16 Vs[2][8 * 512];   // 8 frags (ks*2+dt) of V^T

    const int tid  = threadIdx.x;
    const int lane = tid & 63;
    const int wave = tid >> 6;
    const int l31  = lane & 31;
    const int hl   = lane >> 5;
    const int bh   = blockIdx.x;                      // bh-major: same-head q-tiles share L2
    const int b    = bh >> 4, h = bh & 15;
    const int q0   = blockIdx.y * 128;

    const _Float16* Qg  = Q  + (size_t)(b * SS + q0) * EE + h * DD;
    const _Float16* Kg  = K  + (size_t)(b * SS) * EE + h * DD;
    const _Float16* Vtg = Vt + (size_t)bh * DD * SS;

    // ---- Q fragments: global -> regs, once (B-operand, all 4 k-steps) ----
    f16x8 qf[4];
#pragma unroll
    for (int ks = 0; ks < 4; ++ks)
        qf[ks] = *(const f16x8*)(Qg + (size_t)(wave * 32 + l31) * EE + ks * 16 + hl * 8);

    // per-thread staging source pointers (advance by one tile each iter)
    const _Float16* kp[2];
    const _Float16* vp[2];
#pragma unroll
    for (int p = 0; p < 2; ++p) {
        int f = wave * 2 + p;
        int kvt = f >> 2, ksk = f & 3;            // K frag = kvt*4+ks
        kp[p] = Kg + (size_t)(kvt * 32 + l31) * EE + ksk * 16 + hl * 8;
        int ksv = f >> 1, dt = f & 1;             // V frag = ks*2+dt
        vp[p] = Vtg + (size_t)(dt * 32 + l31) * SS + ksv * 16 + hl * 8;
    }

    // ---- prologue: stage K(0),V(0) into buf0 ----
#pragma unroll
    for (int p = 0; p < 2; ++p) {
        int f = wave * 2 + p;
        async16(&Ks[0][f * 512], kp[p]);
        async16(&Vs[0][f * 512], vp[p]);
    }
    __syncthreads();

    float ls[4] = {0.f, 0.f, 0.f, 0.f};
    f32x16 o0 = {}, o1 = {};

    for (int t = 0; t < NT; ++t) {
        const int buf = t & 1;

        // prefetch K(t+1),V(t+1) into buf^1 (drains at tile-end barrier)
        if (t + 1 < NT) {
#pragma unroll
            for (int p = 0; p < 2; ++p) {
                int f = wave * 2 + p;
                kp[p] += 64 * EE;
                vp[p] += 64;
                async16(&Ks[buf ^ 1][f * 512], kp[p]);
                async16(&Vs[buf ^ 1][f * 512], vp[p]);
            }
        }

        // ---- QK^T: two interleaved 4-deep MFMA chains ----
        f32x16 sa = {}, sb = {};
        __builtin_amdgcn_s_setprio(1);
#pragma unroll
        for (int ks = 0; ks < 4; ++ks) {
            f16x8 a0 = *(const f16x8*)&Ks[buf][ks * 512 + lane * 8];
            f16x8 a1 = *(const f16x8*)&Ks[buf][(4 + ks) * 512 + lane * 8];
            sa = __builtin_amdgcn_mfma_f32_32x32x16_f16(a0, qf[ks], sa, 0, 0, 0);
            sb = __builtin_amdgcn_mfma_f32_32x32x16_f16(a1, qf[ks], sb, 0, 0, 0);
        }
        __builtin_amdgcn_s_setprio(0);

        // ---- softmax + in-register pack, PV per kvt ----
        f16x8 pB[4];
#pragma unroll
        for (int kvt = 0; kvt < 2; ++kvt) {
            const f32x16& s = kvt ? sb : sa;
            float p[16];
#pragma unroll
            for (int r = 0; r < 16; ++r) {
                p[r] = __builtin_amdgcn_exp2f(s[r]);
                ls[r & 3] += p[r];
            }
            int w[8];
#pragma unroll
            for (int i = 0; i < 8; ++i)
                w[i] = __builtin_bit_cast(int, __builtin_amdgcn_cvt_pkrtz(p[2 * i], p[2 * i + 1]));
            asm("v_permlane32_swap_b32 %0, %1" : "+v"(w[0]), "+v"(w[2]));
            asm("v_permlane32_swap_b32 %0, %1" : "+v"(w[1]), "+v"(w[3]));
            asm("v_permlane32_swap_b32 %0, %1" : "+v"(w[4]), "+v"(w[6]));
            asm("v_permlane32_swap_b32 %0, %1" : "+v"(w[5]), "+v"(w[7]));
            int4 lo; lo.x = w[0]; lo.y = w[1]; lo.z = w[2]; lo.w = w[3];
            int4 hi; hi.x = w[4]; hi.y = w[5]; hi.z = w[6]; hi.w = w[7];
            pB[kvt * 2 + 0] = __builtin_bit_cast(f16x8, lo);
            pB[kvt * 2 + 1] = __builtin_bit_cast(f16x8, hi);

            // PV for this kvt's two k-slices (sm of next kvt runs under these)
            __builtin_amdgcn_s_setprio(1);
#pragma unroll
            for (int ks = kvt * 2; ks < kvt * 2 + 2; ++ks) {
                f16x8 v0 = *(const f16x8*)&Vs[buf][(ks * 2 + 0) * 512 + lane * 8];
                o0 = __builtin_amdgcn_mfma_f32_32x32x16_f16(v0, pB[ks], o0, 0, 0, 0);
                f16x8 v1 = *(const f16x8*)&Vs[buf][(ks * 2 + 1) * 512 + lane * 8];
                o1 = __builtin_amdgcn_mfma_f32_32x32x16_f16(v1, pB[ks], o1, 0, 0, 0);
            }
            __builtin_amdgcn_s_setprio(0);
        }

        __syncthreads();   // buf reads done by all waves; buf^1 prefetch drained
    }

    // ---- epilogue: combine partials, reduce across lane-halves, store ----
    float lsum = (ls[0] + ls[1]) + (ls[2] + ls[3]);
    float lt  = lsum + __shfl_xor(lsum, 32);
    float inv = 1.0f / lt;
    _Float16* Og = O + (size_t)(b * SS + q0 + wave * 32 + l31) * EE + h * DD;
#pragma unroll
    for (int dt = 0; dt < 2; ++dt)
#pragma unroll
        for (int g = 0; g < 4; ++g) {
            f16x4 ov;
#pragma unroll
            for (int r = 0; r < 4; ++r) {
                float val = (dt == 0) ? o0[g * 4 + r] : o1[g * 4 + r];
                ov[r] = (_Float16)(val * inv);
            }
            *(f16x4*)&Og[dt * 32 + g * 8 + hl * 4] = ov;
        }
}

extern "C" void kernel_launch(void* const* d_in, const int* in_sizes, int n_in,
                              void* d_out, int out_size, void* d_ws, size_t ws_size,
                              hipStream_t stream) {
    const float* query = (const float*)d_in[0];
    const float* key   = (const float*)d_in[1];
    const float* value = (const float*)d_in[2];
    const float* Wq    = (const float*)d_in[3];
    const float* Wk    = (const float*)d_in[4];
    const float* Wv    = (const float*)d_in[5];
    const float* Wo    = (const float*)d_in[6];
    float* out = (float*)d_out;

    const size_t NE = (size_t)MM * EE;   // 8388608
    const size_t NW = (size_t)EE * EE;   // 1048576
    // ws: Qw,Kw,Vt (48MB) + Wf (8MB) + Qact/O (16MB) = 72 MiB
    _Float16* Qw   = (_Float16*)d_ws;
    _Float16* Kw   = Qw + NE;
    _Float16* Vw   = Kw + NE;            // holds TRANSPOSED V: [B][H][D][S]
    _Float16* Wf   = Vw + NE;            // [4][NW]
    _Float16* Qact = Wf + 4 * NW;        // query fp16; later attn O
    // K/V activations borrow d_out (32MB fp32) — dead before final GEMM writes it
    _Float16* Kact = (_Float16*)d_out;
    _Float16* Vact = Kact + NE;

    dim3 blk(256);
    const int wN8 = (int)(NW / 8), aN8 = (int)(NE / 8);

    // 1) all converts, one launch (weight segments early-exit past wN8)
    cvt_all<<<dim3(aN8 / 256, 7), blk, 0, stream>>>(query, key, value, Wq, Wk, Wv, Wo,
                                                    Qact, Kact, Vact, Wf, aN8, wN8);

    // 2) QKV projections, z=3, band-swizzled (Q folds cs; V stored transposed,
    //    coalesced via LDS bounce)
    gemm_qkv<<<dim3(512, 3), blk, 0, stream>>>(Qact, Kact, Vact, Wf, Qw, MM, EE, EE);

    // 3) attention -> Qact region (bh-major grid for XCD L2 locality)
    attn_kernel<<<dim3(BB * HH, SS / 128), blk, 0, stream>>>(Qw, Kw, Vw, Qact);

    // 4) output projection (writes all of d_out; Kact/Vact dead)
    gemm_wo<<<dim3(512), blk, 0, stream>>>(Qact, Wf + 3 * NW, out, MM, EE, EE);
}